// Round 6
// baseline (745.676 us; speedup 1.0000x reference)
//
#include <hip/hip_runtime.h>
#include <hip/hip_bf16.h>

typedef unsigned short ushort_t;
typedef __attribute__((ext_vector_type(8))) short short8;
typedef __attribute__((ext_vector_type(4))) short short4v;
typedef __attribute__((ext_vector_type(4))) float f32x4;

#define DEVI static __device__ __forceinline__
#define MFMA __builtin_amdgcn_mfma_f32_16x16x32_bf16

DEVI float b2f(ushort_t u) {
    union { unsigned i; float f; } v; v.i = ((unsigned)u) << 16; return v.f;
}
DEVI ushort_t f2b(float f) {
    union { float f; unsigned i; } v; v.f = f;
    unsigned r = v.i + 0x7FFFu + ((v.i >> 16) & 1u);
    return (ushort_t)(r >> 16);
}
DEVI unsigned encf(float f) {  // monotonic float->uint for atomicMax
    unsigned u = __float_as_uint(f);
    return (u & 0x80000000u) ? ~u : (u | 0x80000000u);
}
DEVI float decf(unsigned u) {
    return (u & 0x80000000u) ? __uint_as_float(u & 0x7FFFFFFFu) : __uint_as_float(~u);
}
DEVI bool finitef(float v) { return v > -1e30f && v < 1e30f; }

// async global->LDS, 16B per lane; LDS dest = wave-uniform base + lane*16
DEVI void gload16(const ushort_t* g, ushort_t* l) {
    __builtin_amdgcn_global_load_lds(
        (const __attribute__((address_space(1))) void*)(g),
        (__attribute__((address_space(3))) void*)(l), 16, 0, 0);
}

// ---------------- dtype probe: fl[0]=1 if inputs are fp32, 0 if bf16; fl[1]=stage flags=0 ----
__global__ void k_dtype(const ushort_t* __restrict__ qraw, unsigned* __restrict__ fl) {
    __shared__ unsigned cnt;
    int t = threadIdx.x;
    if (t == 0) cnt = 0;
    __syncthreads();
    unsigned c = 0;
    for (int i = t; i < 2048; i += 256) {
        unsigned e = (qraw[2 * i] >> 7) & 0xFF;
        c += (e >= 90 && e <= 141) ? 1u : 0u;
    }
    atomicAdd(&cnt, c);
    __syncthreads();
    if (t == 0) { fl[0] = (cnt < 1024) ? 1u : 0u; fl[1] = 0u; }
}

// ---------------- ws-too-small sentinel fill ----------------
__global__ void k_fill(ushort_t* __restrict__ out, int n, float val) {
    int i = blockIdx.x * 256 + threadIdx.x;
    if (i < n) out[i] = f2b(val);
}

// ---------------- input fp32->bf16 conversion; no-op when inputs already bf16 ----------------
__global__ void k_cvt(const void* __restrict__ in, ushort_t* __restrict__ out,
                      const unsigned* __restrict__ fl) {
    if (fl[0] == 0) return;                   // bf16 inputs: GEMM reads original directly
    int i = blockIdx.x * 256 + threadIdx.x;   // 8192*256 threads, 8 elems each = 16M
    const float4* p = (const float4*)in + (size_t)i * 2;
    float4 a = p[0], b = p[1];
    short8 o;
    ((ushort_t*)&o)[0] = f2b(a.x); ((ushort_t*)&o)[1] = f2b(a.y);
    ((ushort_t*)&o)[2] = f2b(a.z); ((ushort_t*)&o)[3] = f2b(a.w);
    ((ushort_t*)&o)[4] = f2b(b.x); ((ushort_t*)&o)[5] = f2b(b.y);
    ((ushort_t*)&o)[6] = f2b(b.z); ((ushort_t*)&o)[7] = f2b(b.w);
    *(short8*)(out + (size_t)i * 8) = o;
}

// ---------------- prep: transpose 4 weight matrices + scale proj (dual-dtype) ----------------
__global__ void k_prep(const void* __restrict__ Wq, const void* __restrict__ Wk,
                       const void* __restrict__ Wv, const void* __restrict__ Wo,
                       const void* __restrict__ rf, const unsigned* __restrict__ fl,
                       ushort_t* __restrict__ WT, ushort_t* __restrict__ WTo,
                       ushort_t* __restrict__ projS) {
    bool f32 = fl[0] != 0;
    int id = blockIdx.x, t = threadIdx.x;
    if (id == 1024) {  // fold data_normalizer 64^-0.25 into proj
        for (int i = t; i < 256 * 64; i += 256) {
            float x = f32 ? ((const float*)rf)[i] : b2f(((const ushort_t*)rf)[i]);
            projS[i] = f2b(x * 0.35355339f);
        }
        return;
    }
    int wsel = id >> 8;
    const void* W = wsel == 0 ? Wq : (wsel == 1 ? Wk : (wsel == 2 ? Wv : Wo));
    ushort_t* out = (wsel == 3) ? WTo : (WT + (size_t)wsel * 1024 * 1024);
    int tile = id & 255;
    int tr = (tile >> 4) * 64, tc = (tile & 15) * 64;
    __shared__ ushort_t s[64][65];
    int r = t >> 2, c = (t & 3) * 16;
    ushort_t vals[16];
    if (f32) {
        const float* src = (const float*)W + (size_t)(tr + r) * 1024 + tc + c;
        for (int u = 0; u < 4; u++) {
            float4 x = ((const float4*)src)[u];
            vals[4 * u + 0] = f2b(x.x); vals[4 * u + 1] = f2b(x.y);
            vals[4 * u + 2] = f2b(x.z); vals[4 * u + 3] = f2b(x.w);
        }
    } else {
        const ushort_t* src = (const ushort_t*)W + (size_t)(tr + r) * 1024 + tc + c;
        short8 v0 = ((const short8*)src)[0], v1 = ((const short8*)src)[1];
        for (int j = 0; j < 8; j++) { vals[j] = ((ushort_t*)&v0)[j]; vals[8 + j] = ((ushort_t*)&v1)[j]; }
    }
    for (int j = 0; j < 16; j++) s[r][c + j] = vals[j];
    __syncthreads();
    ushort_t tmp[16];
    for (int j = 0; j < 16; j++) tmp[j] = s[c + j][r];  // out[tc+r][tr+c+j] = W[tr+c+j][tc+r]
    short8 o0, o1;
    for (int j = 0; j < 8; j++) { ((ushort_t*)&o0)[j] = tmp[j]; ((ushort_t*)&o1)[j] = tmp[8 + j]; }
    short8* dst = (short8*)(out + (size_t)(tc + r) * 1024 + tr + c);
    dst[0] = o0; dst[1] = o1;
}

// ---------------- GEMM (gload + 2-phase dbuf): C = A @ Bt^T + bias ----------------
// T3-minimum recipe: issue next-tile global_load_lds BEFORE computing current tile;
// one __syncthreads() per K-step (implicit vmcnt(0) waits on loads that had the
// whole MFMA phase to land). A bf16 = Abf if fp32 inputs else Aor.
__global__ __launch_bounds__(256) void k_gemm_g(const ushort_t* __restrict__ Abf,
                                                const ushort_t* __restrict__ Aor,
                                                const ushort_t* __restrict__ Bt,
                                                const void* __restrict__ bias,
                                                void* __restrict__ C,
                                                const unsigned* __restrict__ fl,
                                                int cFinal) {
    constexpr int K = 1024, NC = 1024;
    __shared__ ushort_t sA[2][128][32];   // linear row-major, 64B rows (gload dest)
    __shared__ ushort_t sB[2][128][32];
    bool f32 = fl[0] != 0;
    const ushort_t* A = f32 ? Abf : Aor;
    unsigned flags = cFinal ? fl[1] : 0u;
    int t = threadIdx.x;
    int m0 = blockIdx.x * 128, n0 = blockIdx.y * 128;
    int w = t >> 6, lane = t & 63, lr = lane & 15, quad = lane >> 4, ko = quad * 8;
    int wm = (w & 1) * 64, wn = (w >> 1) * 64;
    // wave w stages 32 rows of A and B (two 16-row chunks); lane l -> LDS base + l*16.
    int srow = lane >> 2, scol = (lane & 3) * 8;
    const ushort_t* aP = A  + (size_t)(m0 + w * 32 + srow) * K + scol;
    const ushort_t* bP = Bt + (size_t)(n0 + w * 32 + srow) * K + scol;
    // prologue: stage tile 0 into buf 0
    gload16(aP, &sA[0][w * 32][0]);            gload16(bP, &sB[0][w * 32][0]);
    gload16(aP + 16 * K, &sA[0][w * 32 + 16][0]); gload16(bP + 16 * K, &sB[0][w * 32 + 16][0]);
    __syncthreads();
    f32x4 acc[4][4] = {};
    int cur = 0;
    for (int kt = 0; kt < K; kt += 32) {
        if (kt + 32 < K) {                    // prefetch next tile into other buffer
            const ushort_t* an = aP + kt + 32;
            const ushort_t* bn = bP + kt + 32;
            int nxt = cur ^ 1;
            gload16(an, &sA[nxt][w * 32][0]);            gload16(bn, &sB[nxt][w * 32][0]);
            gload16(an + 16 * K, &sA[nxt][w * 32 + 16][0]); gload16(bn + 16 * K, &sB[nxt][w * 32 + 16][0]);
        }
        short8 af[4], bf[4];
        for (int i = 0; i < 4; i++) af[i] = *(const short8*)&sA[cur][wm + i * 16 + lr][ko];
        for (int j = 0; j < 4; j++) bf[j] = *(const short8*)&sB[cur][wn + j * 16 + lr][ko];
        for (int i = 0; i < 4; i++)
            for (int j = 0; j < 4; j++)
                acc[i][j] = MFMA(af[i], bf[j], acc[i][j], 0, 0, 0);
        __syncthreads();                      // drains vmcnt(0): next tile resident
        cur ^= 1;
    }
    for (int j = 0; j < 4; j++) {
        int col = n0 + wn + j * 16 + lr;
        float bv = f32 ? ((const float*)bias)[col] : b2f(((const ushort_t*)bias)[col]);
        for (int i = 0; i < 4; i++) {
            int rowb = m0 + wm + i * 16 + quad * 4;
            for (int r = 0; r < 4; r++) {
                float val = acc[i][j][r] + bv;
                if (cFinal) {
                    if (flags) val = 100.0f * (float)flags;          // stage-flag sentinel
                    else if (!finitef(val)) val = 2000.0f;           // NaN tripwire
                }
                size_t idx = (size_t)(rowb + r) * NC + col;
                if (cFinal && f32) ((float*)C)[idx] = val;
                else ((ushort_t*)C)[idx] = f2b(val);
            }
        }
    }
}

// ---------------- init: kvT = 0 except row64 = ratio*eps*L; ----------------
__global__ void k_init(float* __restrict__ kvT, unsigned* __restrict__ mxk) {
    int bid = blockIdx.x, t = threadIdx.x;
    if (bid == 5120) { if (t < 64) mxk[t] = 0u; return; }
    int idx = bid * 256 + t;                    // 64*80*256 total
    int row = (idx >> 8) % 80;
    kvT[idx] = (row == 64) ? 2.56e-4f : 0.0f;   // 0.0625 * 1e-6 * 4096
}

// ---------------- k max pre-pass: max over l,m of dd_k per bh ----------------
__global__ __launch_bounds__(256) void k_kmax(const ushort_t* __restrict__ kproj,
                                              const ushort_t* __restrict__ projS,
                                              unsigned* __restrict__ mxk) {
    __shared__ ushort_t sB[64][72];
    __shared__ float wm4[4];
    int t = threadIdx.x, l0 = blockIdx.x * 64, bh = blockIdx.y;
    int b = bh >> 4, h = bh & 15;
    int w = t >> 6, lane = t & 63, lr = lane & 15, ko = (lane >> 4) * 8;
    short8 af[4][2];
    for (int i = 0; i < 4; i++)
        for (int ks = 0; ks < 2; ks++)
            af[i][ks] = *(const short8*)(projS + (size_t)(w * 64 + i * 16 + lr) * 64 + ks * 32 + ko);
    {
        int r = t >> 2, c = (t & 3) * 16;
        const short8* p = (const short8*)(kproj + (size_t)(b * 4096 + l0 + r) * 1024 + h * 64 + c);
        *(short8*)&sB[r][c] = p[0];
        *(short8*)&sB[r][c + 8] = p[1];
    }
    __syncthreads();
    f32x4 acc[4][4] = {};
    for (int j = 0; j < 4; j++)
        for (int ks = 0; ks < 2; ks++) {
            short8 bf = *(const short8*)&sB[j * 16 + lr][ks * 32 + ko];
            for (int i = 0; i < 4; i++)
                acc[i][j] = MFMA(af[i][ks], bf, acc[i][j], 0, 0, 0);
        }
    float vmax = -1e30f;
    for (int i = 0; i < 4; i++)
        for (int j = 0; j < 4; j++)
            for (int r = 0; r < 4; r++) vmax = fmaxf(vmax, acc[i][j][r]);
    for (int off = 32; off; off >>= 1) vmax = fmaxf(vmax, __shfl_xor(vmax, off, 64));
    if (lane == 0) wm4[w] = vmax;
    __syncthreads();
    if (t == 0) {
        float m = fmaxf(fmaxf(wm4[0], wm4[1]), fmaxf(wm4[2], wm4[3]));
        atomicMax(mxk + bh, encf(m));
    }
}

// ---------------- fused kv: dd=projS@k^T -> exp -> kv += vT'@expdd^T ----------
__global__ __launch_bounds__(256) void k_kv(const ushort_t* __restrict__ kproj,
                                            const ushort_t* __restrict__ vproj,
                                            const ushort_t* __restrict__ projS,
                                            const unsigned* __restrict__ mxk,
                                            float* __restrict__ kvT) {
    __shared__ ushort_t sVT[80][40];
    __shared__ float    sdk[32];
    __shared__ ushort_t sK[32][72];
    __shared__ ushort_t sV[32][72];
    __shared__ ushort_t sE[256][40];
    int t = threadIdx.x, kz = blockIdx.x, bh = blockIdx.y;
    int b = bh >> 4, h = bh & 15;
    int w = t >> 6, lane = t & 63, lr = lane & 15, quad = lane >> 4, ko = quad * 8;
    float mx = decf(mxk[bh]);
    short8 af1[4][2];
    for (int i = 0; i < 4; i++)
        for (int ks = 0; ks < 2; ks++)
            af1[i][ks] = *(const short8*)(projS + (size_t)(w * 64 + i * 16 + lr) * 64 + ks * 32 + ko);
    // constant sVT rows 64..79 (identity row 64 for normalizer, zeros) -- written once
    if (t < 128) {
        int rr = 64 + (t >> 3), cc = (t & 7) * 4;
        ushort_t val = (rr == 64) ? (ushort_t)0x3F80 : (ushort_t)0;
        for (int u = 0; u < 4; u++) sVT[rr][cc + u] = val;
    }
    f32x4 acc[5][4] = {};
    for (int lc = kz * 512; lc < kz * 512 + 512; lc += 32) {
        __syncthreads();
        {
            int r = t >> 3, c = (t & 7) * 8;
            *(short8*)&sK[r][c] = *(const short8*)(kproj + (size_t)(b * 4096 + lc + r) * 1024 + h * 64 + c);
            *(short8*)&sV[r][c] = *(const short8*)(vproj + (size_t)(b * 4096 + lc + r) * 1024 + h * 64 + c);
        }
        __syncthreads();
        {   // parallel sum-of-squares: 8 threads/row, one short8 each, 3-level shfl
            int row = t >> 3, seg = t & 7;
            short8 x = *(const short8*)&sK[row][seg * 8];
            float s = 0.f;
            for (int u = 0; u < 8; u++) { float f = b2f(((ushort_t*)&x)[u]); s += f * f; }
            s += __shfl_xor(s, 1, 64);
            s += __shfl_xor(s, 2, 64);
            s += __shfl_xor(s, 4, 64);
            if (seg == 0) sdk[row] = 0.0625f * s;
        }
        short8 bf1[2][2];
        for (int j = 0; j < 2; j++)
            for (int ks = 0; ks < 2; ks++)
                bf1[j][ks] = *(const short8*)&sK[j * 16 + lr][ks * 32 + ko];
        f32x4 acc1[4][2] = {};
        for (int i = 0; i < 4; i++)
            for (int ks = 0; ks < 2; ks++)
                for (int j = 0; j < 2; j++)
                    acc1[i][j] = MFMA(af1[i][ks], bf1[j][ks], acc1[i][j], 0, 0, 0);
        {
            int d2 = t >> 2, ls = (t & 3) * 8;
            short8 pk;
            for (int u = 0; u < 8; u++) ((ushort_t*)&pk)[u] = sV[ls + u][d2];
            *(short8*)&sVT[d2][ls] = pk;
        }
        __syncthreads();
        for (int i = 0; i < 4; i++)
            for (int j = 0; j < 2; j++) {
                int l = j * 16 + lr;
                float dkl = sdk[l];
                for (int r = 0; r < 4; r++) {
                    int m = w * 64 + i * 16 + quad * 4 + r;
                    sE[m][l] = f2b(0.0625f * __expf(acc1[i][j][r] - dkl - mx));
                }
            }
        __syncthreads();
        short8 af2[5], bf2[4];
        for (int i = 0; i < 5; i++) af2[i] = *(const short8*)&sVT[i * 16 + lr][ko];
        for (int j = 0; j < 4; j++) bf2[j] = *(const short8*)&sE[w * 64 + j * 16 + lr][ko];
        for (int i = 0; i < 5; i++)
            for (int j = 0; j < 4; j++)
                acc[i][j] = MFMA(af2[i], bf2[j], acc[i][j], 0, 0, 0);
    }
    float* out = kvT + (size_t)bh * 80 * 256;
    for (int i = 0; i < 5; i++)
        for (int j = 0; j < 4; j++)
            for (int r = 0; r < 4; r++)
                atomicAdd(out + (size_t)(i * 16 + quad * 4 + r) * 256 + (w * 64 + j * 16 + lr),
                          acc[i][j][r]);
}

// ---------------- kvT finite scan + f32->bf16 convert -> fl[1] bit0 ----------------
__global__ void k_scan(const float* __restrict__ kvT, ushort_t* __restrict__ kvbf,
                       unsigned* __restrict__ fl) {
    int i4 = (blockIdx.x * 256 + threadIdx.x) * 4;   // grid 1280 * 256 * 4 = 64*80*256
    f32x4 v = *(const f32x4*)(kvT + i4);
    unsigned bad = 0;
    short4v o;
    for (int u = 0; u < 4; u++) {
        bad |= finitef(v[u]) ? 0u : 1u;
        ((ushort_t*)&o)[u] = f2b(v[u]);
    }
    if (bad) atomicOr(fl + 1, 1u);
    *(short4v*)(kvbf + i4) = o;
}

// ---------------- fused ddq + row-softmax-kernel + av + normalize ----------------
// kv panel (80x256 bf16 = 40 KB) staged once per block into LDS (aliased over dead sQ
// region); loads issued before QK MFMAs so HBM/L2 latency hides under compute (T14).
__global__ __launch_bounds__(256) void k_qav(const ushort_t* __restrict__ qproj,
                                             const ushort_t* __restrict__ projS,
                                             const ushort_t* __restrict__ kvbf,
                                             unsigned* __restrict__ fl,
                                             ushort_t* __restrict__ attn) {
    union KvQ { ushort_t kv[80][264]; ushort_t q[64][72]; };
    __shared__ KvQ sA;                 // 42240 B; q[64][72] (9216 B) aliases the front
    __shared__ ushort_t sQP[64][264];  // 33792 B
    __shared__ float    sdq[64];
    int t = threadIdx.x, l0 = blockIdx.x * 64, bh = blockIdx.y;
    int b = bh >> 4, h = bh & 15;
    int w = t >> 6, lane = t & 63, lr = lane & 15, quad = lane >> 4, ko = quad * 8;
    // stage Q tile
    {
        int r = t >> 2, c = (t & 3) * 16;
        const short8* p = (const short8*)(qproj + (size_t)(b * 4096 + l0 + r) * 1024 + h * 64 + c);
        *(short8*)&sA.q[r][c] = p[0];
        *(short8*)&sA.q[r][c + 8] = p[1];
    }
    // issue kv loads now; they complete under the QK MFMA phase
    short8 kvreg[10];
    const ushort_t* kvsrc = kvbf + (size_t)bh * 80 * 256;
    #pragma unroll
    for (int i = 0; i < 10; i++)
        kvreg[i] = *(const short8*)(kvsrc + (size_t)(i * 256 + t) * 8);
    __syncthreads();
    // A fragments + parallel row sum-of-squares (all 256 threads)
    short8 af[2];
    for (int ks = 0; ks < 2; ks++) af[ks] = *(const short8*)&sA.q[w * 16 + lr][ks * 32 + ko];
    {
        int row = t >> 2, seg = t & 3;
        short8 x0 = *(const short8*)&sA.q[row][seg * 16];
        short8 x1 = *(const short8*)&sA.q[row][seg * 16 + 8];
        float s = 0.f;
        for (int u = 0; u < 8; u++) {
            float a = b2f(((ushort_t*)&x0)[u]), c2 = b2f(((ushort_t*)&x1)[u]);
            s += a * a + c2 * c2;
        }
        s += __shfl_xor(s, 1, 64);
        s += __shfl_xor(s, 2, 64);
        if ((t & 3) == 0) sdq[row] = 0.0625f * s;
    }
    __syncthreads();   // all waves done reading sA.q; sdq visible
    // QK feature MFMAs (no LDS use -> kv loads in flight underneath)
    f32x4 acc[16] = {};
    for (int j = 0; j < 16; j++)
        for (int ks = 0; ks < 2; ks++) {
            short8 bf = *(const short8*)(projS + (size_t)(j * 16 + lr) * 64 + ks * 32 + ko);
            acc[j] = MFMA(af[ks], bf, acc[j], 0, 0, 0);
        }
    // write kv panel into LDS (overwrites dead q region)
    #pragma unroll
    for (int i = 0; i < 10; i++) {
        int c = i * 256 + t;
        *(short8*)&sA.kv[c >> 5][(c & 31) * 8] = kvreg[i];
    }
    // row max + exp features
    int rows0 = w * 16 + quad * 4;
    float rm[4], dq[4];
    for (int r = 0; r < 4; r++) {
        float m = -1e30f;
        for (int j = 0; j < 16; j++) m = fmaxf(m, acc[j][r]);
        for (int off = 1; off < 16; off <<= 1) m = fmaxf(m, __shfl_xor(m, off, 64));
        rm[r] = m;
        dq[r] = sdq[rows0 + r];
    }
    for (int j = 0; j < 16; j++)
        for (int r = 0; r < 4; r++)
            sQP[rows0 + r][j * 16 + lr] = f2b(0.0625f * (__expf(acc[j][r] - dq[r] - rm[r]) + 1e-6f));
    __syncthreads();   // kv + sQP visible
    // PV: pure LDS-fed MFMA
    f32x4 acc2[5] = {};
    for (int kt = 0; kt < 8; kt++) {
        short8 af2 = *(const short8*)&sQP[w * 16 + lr][kt * 32 + ko];
        #pragma unroll
        for (int j = 0; j < 5; j++) {
            short8 bf2 = *(const short8*)&sA.kv[j * 16 + lr][kt * 32 + ko];
            acc2[j] = MFMA(af2, bf2, acc2[j], 0, 0, 0);
        }
    }
    for (int r = 0; r < 4; r++) {
        float nv = __shfl(acc2[4][r], lane & 48, 64);  // kv row 64 = normalizer
        bool badn = !(nv > 0.0f && nv < 1e30f);
        if (badn) atomicOr(fl + 1, 2u);
        float inv = badn ? 0.0f : 1.0f / nv;
        int row = l0 + rows0 + r;
        for (int j = 0; j < 4; j++) {
            float outv = acc2[j][r] * inv;
            if (!finitef(outv)) { outv = 0.0f; atomicOr(fl + 1, 4u); }
            attn[(size_t)(b * 4096 + row) * 1024 + h * 64 + j * 16 + lr] = f2b(outv);
        }
    }
}

extern "C" void kernel_launch(void* const* d_in, const int* in_sizes, int n_in,
                              void* d_out, int out_size, void* d_ws, size_t ws_size,
                              hipStream_t stream) {
    const void* q  = d_in[0];
    const void* k  = d_in[1];
    const void* v  = d_in[2];
    const void* Wq = d_in[3];
    const void* bq = d_in[4];
    const void* Wk = d_in[5];
    const void* bk = d_in[6];
    const void* Wv = d_in[7];
    const void* bv = d_in[8];
    const void* Wo = d_in[9];
    const void* bo = d_in[10];
    const void* rf = d_in[11];

    char* wsp = (char*)d_ws;
    size_t o = 0;
    auto alloc = [&](size_t bytes) { void* p = wsp + o; o += (bytes + 255) & ~(size_t)255; return p; };
    unsigned* fl    = (unsigned*)alloc(256);                      // [0]=dtype, [1]=stage flags
    ushort_t* WT    = (ushort_t*)alloc(3ull * 1024 * 1024 * 2);   // 6.3 MB  Wq/Wk/Wv transposed
    ushort_t* WTo   = (ushort_t*)alloc(1024ull * 1024 * 2);       // 2.1 MB
    ushort_t* projS = (ushort_t*)alloc(256 * 64 * 2);
    ushort_t* kproj = (ushort_t*)alloc(16384ull * 1024 * 2);      // 32 MB (reused as attn)
    ushort_t* vproj = (ushort_t*)alloc(16384ull * 1024 * 2);      // 32 MB
    unsigned* mxk   = (unsigned*)alloc(64 * 4);
    float*    kvT   = (float*)alloc(64ull * 80 * 256 * 4);        // 5.2 MB
    ushort_t* kvbf  = (ushort_t*)alloc(64ull * 80 * 256 * 2);     // 2.6 MB bf16 kv panel
    // d_out lower 32 MB (valid for either output dtype): v/k cvt staging, then qproj.
    // d_out upper 32 MB: q cvt staging -- written ONLY on the fp32 path (device-guarded
    // k_cvt), where d_out is 64 MB. On the bf16 path k_cvt is a no-op and the GEMM
    // reads the original q pointer.
    ushort_t* stg   = (ushort_t*)d_out;
    ushort_t* stgHi = (ushort_t*)d_out + 16777216;   // byte offset 32MB
    ushort_t* qproj = (ushort_t*)d_out;
    ushort_t* attn  = kproj;             // kproj dead after k_kv; k_qav never reads kproj

    if (ws_size < o) {  // workspace too small -> report budget in MB as sentinel
        k_fill<<<dim3((out_size + 255) / 256), 256, 0, stream>>>((ushort_t*)d_out, out_size,
                                                                 (float)(ws_size >> 20));
        return;
    }

    k_dtype<<<dim3(1), 256, 0, stream>>>((const ushort_t*)q, fl);
    k_prep<<<dim3(1025), 256, 0, stream>>>(Wq, Wk, Wv, Wo, rf, fl, WT, WTo, projS);

    // v, k: cvt into stg (lower 32MB; no-op if bf16), gload GEMM.
    k_cvt<<<dim3(8192), 256, 0, stream>>>(v, stg, fl);
    k_gemm_g<<<dim3(128, 8), 256, 0, stream>>>(stg, (const ushort_t*)v,
                                               WT + 2ull * 1048576, bv, vproj, fl, 0);
    k_cvt<<<dim3(8192), 256, 0, stream>>>(k, stg, fl);
    k_gemm_g<<<dim3(128, 8), 256, 0, stream>>>(stg, (const ushort_t*)k,
                                               WT + 1ull * 1048576, bk, kproj, fl, 0);
    // q: cvt into UPPER 32MB (fp32 path only), GEMM reads upper / writes lower (disjoint).
    k_cvt<<<dim3(8192), 256, 0, stream>>>(q, stgHi, fl);
    k_gemm_g<<<dim3(128, 8), 256, 0, stream>>>(stgHi, (const ushort_t*)q,
                                               WT + 0ull * 1048576, bq, qproj, fl, 0);

    k_init<<<dim3(5121), 256, 0, stream>>>(kvT, mxk);
    k_kmax<<<dim3(64, 64), 256, 0, stream>>>(kproj, projS, mxk);
    k_kv<<<dim3(8, 64), 256, 0, stream>>>(kproj, vproj, projS, mxk, kvT);
    k_scan<<<dim3(1280), 256, 0, stream>>>(kvT, kvbf, fl);
    k_qav<<<dim3(64, 64), 256, 0, stream>>>(qproj, projS, kvbf, fl, attn);
    k_gemm_g<<<dim3(128, 8), 256, 0, stream>>>(attn, attn, WTo, bo, d_out, fl, 1);
}

// Round 7
// 702.694 us; speedup vs baseline: 1.0612x; 1.0612x over previous
//
#include <hip/hip_runtime.h>
#include <hip/hip_bf16.h>

typedef unsigned short ushort_t;
typedef __attribute__((ext_vector_type(8))) short short8;
typedef __attribute__((ext_vector_type(4))) short short4v;
typedef __attribute__((ext_vector_type(4))) float f32x4;

#define DEVI static __device__ __forceinline__
#define MFMA __builtin_amdgcn_mfma_f32_16x16x32_bf16

DEVI float b2f(ushort_t u) {
    union { unsigned i; float f; } v; v.i = ((unsigned)u) << 16; return v.f;
}
DEVI ushort_t f2b(float f) {
    union { float f; unsigned i; } v; v.f = f;
    unsigned r = v.i + 0x7FFFu + ((v.i >> 16) & 1u);
    return (ushort_t)(r >> 16);
}
DEVI unsigned encf(float f) {  // monotonic float->uint for atomicMax
    unsigned u = __float_as_uint(f);
    return (u & 0x80000000u) ? ~u : (u | 0x80000000u);
}
DEVI float decf(unsigned u) {
    return (u & 0x80000000u) ? __uint_as_float(u & 0x7FFFFFFFu) : __uint_as_float(~u);
}
DEVI bool finitef(float v) { return v > -1e30f && v < 1e30f; }

// async global->LDS, 16B per lane; LDS dest = wave-uniform base + lane*16
DEVI void gload16(const ushort_t* g, ushort_t* l) {
    __builtin_amdgcn_global_load_lds(
        (const __attribute__((address_space(1))) void*)(g),
        (__attribute__((address_space(3))) void*)(l), 16, 0, 0);
}

// ---------------- dtype probe: fl[0]=1 if inputs are fp32, 0 if bf16; fl[1]=stage flags=0 ----
__global__ void k_dtype(const ushort_t* __restrict__ qraw, unsigned* __restrict__ fl) {
    __shared__ unsigned cnt;
    int t = threadIdx.x;
    if (t == 0) cnt = 0;
    __syncthreads();
    unsigned c = 0;
    for (int i = t; i < 2048; i += 256) {
        unsigned e = (qraw[2 * i] >> 7) & 0xFF;
        c += (e >= 90 && e <= 141) ? 1u : 0u;
    }
    atomicAdd(&cnt, c);
    __syncthreads();
    if (t == 0) { fl[0] = (cnt < 1024) ? 1u : 0u; fl[1] = 0u; }
}

// ---------------- ws-too-small sentinel fill ----------------
__global__ void k_fill(ushort_t* __restrict__ out, int n, float val) {
    int i = blockIdx.x * 256 + threadIdx.x;
    if (i < n) out[i] = f2b(val);
}

// ---------------- input fp32->bf16 conversion; no-op when inputs already bf16 ----------------
__global__ void k_cvt(const void* __restrict__ in, ushort_t* __restrict__ out,
                      const unsigned* __restrict__ fl) {
    if (fl[0] == 0) return;                   // bf16 inputs: GEMM reads original directly
    int i = blockIdx.x * 256 + threadIdx.x;   // 8192*256 threads, 8 elems each = 16M
    const float4* p = (const float4*)in + (size_t)i * 2;
    float4 a = p[0], b = p[1];
    short8 o;
    ((ushort_t*)&o)[0] = f2b(a.x); ((ushort_t*)&o)[1] = f2b(a.y);
    ((ushort_t*)&o)[2] = f2b(a.z); ((ushort_t*)&o)[3] = f2b(a.w);
    ((ushort_t*)&o)[4] = f2b(b.x); ((ushort_t*)&o)[5] = f2b(b.y);
    ((ushort_t*)&o)[6] = f2b(b.z); ((ushort_t*)&o)[7] = f2b(b.w);
    *(short8*)(out + (size_t)i * 8) = o;
}

// ---------------- prep: transpose 4 weight matrices + scale proj (dual-dtype) ----------------
__global__ void k_prep(const void* __restrict__ Wq, const void* __restrict__ Wk,
                       const void* __restrict__ Wv, const void* __restrict__ Wo,
                       const void* __restrict__ rf, const unsigned* __restrict__ fl,
                       ushort_t* __restrict__ WT, ushort_t* __restrict__ WTo,
                       ushort_t* __restrict__ projS) {
    bool f32 = fl[0] != 0;
    int id = blockIdx.x, t = threadIdx.x;
    if (id == 1024) {  // fold data_normalizer 64^-0.25 into proj
        for (int i = t; i < 256 * 64; i += 256) {
            float x = f32 ? ((const float*)rf)[i] : b2f(((const ushort_t*)rf)[i]);
            projS[i] = f2b(x * 0.35355339f);
        }
        return;
    }
    int wsel = id >> 8;
    const void* W = wsel == 0 ? Wq : (wsel == 1 ? Wk : (wsel == 2 ? Wv : Wo));
    ushort_t* out = (wsel == 3) ? WTo : (WT + (size_t)wsel * 1024 * 1024);
    int tile = id & 255;
    int tr = (tile >> 4) * 64, tc = (tile & 15) * 64;
    __shared__ ushort_t s[64][65];
    int r = t >> 2, c = (t & 3) * 16;
    ushort_t vals[16];
    if (f32) {
        const float* src = (const float*)W + (size_t)(tr + r) * 1024 + tc + c;
        for (int u = 0; u < 4; u++) {
            float4 x = ((const float4*)src)[u];
            vals[4 * u + 0] = f2b(x.x); vals[4 * u + 1] = f2b(x.y);
            vals[4 * u + 2] = f2b(x.z); vals[4 * u + 3] = f2b(x.w);
        }
    } else {
        const ushort_t* src = (const ushort_t*)W + (size_t)(tr + r) * 1024 + tc + c;
        short8 v0 = ((const short8*)src)[0], v1 = ((const short8*)src)[1];
        for (int j = 0; j < 8; j++) { vals[j] = ((ushort_t*)&v0)[j]; vals[8 + j] = ((ushort_t*)&v1)[j]; }
    }
    for (int j = 0; j < 16; j++) s[r][c + j] = vals[j];
    __syncthreads();
    ushort_t tmp[16];
    for (int j = 0; j < 16; j++) tmp[j] = s[c + j][r];  // out[tc+r][tr+c+j] = W[tr+c+j][tc+r]
    short8 o0, o1;
    for (int j = 0; j < 8; j++) { ((ushort_t*)&o0)[j] = tmp[j]; ((ushort_t*)&o1)[j] = tmp[8 + j]; }
    short8* dst = (short8*)(out + (size_t)(tc + r) * 1024 + tr + c);
    dst[0] = o0; dst[1] = o1;
}

// ---------------- GEMM (gload): C = A @ Bt^T + bias; A bf16 (Abf if fp32-in else Aor) ----
// m97 structure: linear LDS tiles staged via global_load_lds dwordx4 (4/wave/K-step).
__global__ __launch_bounds__(256) void k_gemm_g(const ushort_t* __restrict__ Abf,
                                                const ushort_t* __restrict__ Aor,
                                                const ushort_t* __restrict__ Bt,
                                                const void* __restrict__ bias,
                                                void* __restrict__ C,
                                                const unsigned* __restrict__ fl,
                                                int cFinal) {
    constexpr int K = 1024, NC = 1024;
    __shared__ ushort_t sA[128][32];   // linear row-major, 64B rows (global_load_lds dest)
    __shared__ ushort_t sB[128][32];
    bool f32 = fl[0] != 0;
    const ushort_t* A = f32 ? Abf : Aor;
    unsigned flags = cFinal ? fl[1] : 0u;
    int t = threadIdx.x;
    int m0 = blockIdx.x * 128, n0 = blockIdx.y * 128;
    int w = t >> 6, lane = t & 63, lr = lane & 15, quad = lane >> 4, ko = quad * 8;
    int wm = (w & 1) * 64, wn = (w >> 1) * 64;
    // wave w stages 32 rows of A and B (two 16-row chunks each); lane l -> LDS base+l*16.
    int srow = lane >> 2, scol = (lane & 3) * 8;
    const ushort_t* a0 = A  + (size_t)(m0 + w * 32 + srow) * K + scol;
    const ushort_t* a1 = a0 + 16 * K;
    const ushort_t* b0 = Bt + (size_t)(n0 + w * 32 + srow) * K + scol;
    const ushort_t* b1 = b0 + 16 * K;
    ushort_t* la0 = &sA[w * 32][0];
    ushort_t* la1 = &sA[w * 32 + 16][0];
    ushort_t* lb0 = &sB[w * 32][0];
    ushort_t* lb1 = &sB[w * 32 + 16][0];
    f32x4 acc[4][4] = {};
    for (int kt = 0; kt < K; kt += 32) {
        gload16(a0, la0); gload16(b0, lb0);
        gload16(a1, la1); gload16(b1, lb1);
        a0 += 32; a1 += 32; b0 += 32; b1 += 32;
        __syncthreads();
        short8 af[4], bf[4];
        for (int i = 0; i < 4; i++) af[i] = *(const short8*)&sA[wm + i * 16 + lr][ko];
        for (int j = 0; j < 4; j++) bf[j] = *(const short8*)&sB[wn + j * 16 + lr][ko];
        for (int i = 0; i < 4; i++)
            for (int j = 0; j < 4; j++)
                acc[i][j] = MFMA(af[i], bf[j], acc[i][j], 0, 0, 0);
        __syncthreads();
    }
    for (int j = 0; j < 4; j++) {
        int col = n0 + wn + j * 16 + lr;
        float bv = f32 ? ((const float*)bias)[col] : b2f(((const ushort_t*)bias)[col]);
        for (int i = 0; i < 4; i++) {
            int rowb = m0 + wm + i * 16 + quad * 4;
            for (int r = 0; r < 4; r++) {
                float val = acc[i][j][r] + bv;
                if (cFinal) {
                    if (flags) val = 100.0f * (float)flags;          // stage-flag sentinel
                    else if (!finitef(val)) val = 2000.0f;           // NaN tripwire
                }
                size_t idx = (size_t)(rowb + r) * NC + col;
                if (cFinal && f32) ((float*)C)[idx] = val;
                else ((ushort_t*)C)[idx] = f2b(val);
            }
        }
    }
}

// ---------------- GEMM (reg-A): A dual-dtype reg-staged, B via gload; C bf16 ----------
// Used only for the q projection (its staging region IS the output buffer).
__global__ __launch_bounds__(256) void k_gemm_r(const void* __restrict__ A,
                                                const ushort_t* __restrict__ Bt,
                                                const void* __restrict__ bias,
                                                ushort_t* __restrict__ C,
                                                const unsigned* __restrict__ fl) {
    constexpr int K = 1024, NC = 1024;
    __shared__ ushort_t sA[128][40];   // padded: reg-staged ds_writes
    __shared__ ushort_t sB[128][32];   // linear: gload dest
    bool f32 = fl[0] != 0;
    int t = threadIdx.x;
    int m0 = blockIdx.x * 128, n0 = blockIdx.y * 128;
    int ar = t >> 1, ac = (t & 1) * 16;
    int w = t >> 6, lane = t & 63, lr = lane & 15, quad = lane >> 4, ko = quad * 8;
    int wm = (w & 1) * 64, wn = (w >> 1) * 64;
    int srow = lane >> 2, scol = (lane & 3) * 8;
    const ushort_t* b0 = Bt + (size_t)(n0 + w * 32 + srow) * K + scol;
    const ushort_t* b1 = b0 + 16 * K;
    ushort_t* lb0 = &sB[w * 32][0];
    ushort_t* lb1 = &sB[w * 32 + 16][0];
    f32x4 acc[4][4] = {};
    for (int kt = 0; kt < K; kt += 32) {
        gload16(b0, lb0); gload16(b1, lb1);
        b0 += 32; b1 += 32;
        ushort_t av[16];
        if (f32) {
            const float* pf = (const float*)A + (size_t)(m0 + ar) * K + ac + kt;
            for (int u = 0; u < 4; u++) {
                float4 x = ((const float4*)pf)[u];
                av[4 * u + 0] = f2b(x.x); av[4 * u + 1] = f2b(x.y);
                av[4 * u + 2] = f2b(x.z); av[4 * u + 3] = f2b(x.w);
            }
        } else {
            const ushort_t* ph = (const ushort_t*)A + (size_t)(m0 + ar) * K + ac + kt;
            short8 a0 = ((const short8*)ph)[0], a1 = ((const short8*)ph)[1];
            for (int j = 0; j < 8; j++) { av[j] = ((ushort_t*)&a0)[j]; av[8 + j] = ((ushort_t*)&a1)[j]; }
        }
        *(short8*)&sA[ar][ac] = *(short8*)&av[0];
        *(short8*)&sA[ar][ac + 8] = *(short8*)&av[8];
        __syncthreads();
        short8 af[4], bf[4];
        for (int i = 0; i < 4; i++) af[i] = *(const short8*)&sA[wm + i * 16 + lr][ko];
        for (int j = 0; j < 4; j++) bf[j] = *(const short8*)&sB[wn + j * 16 + lr][ko];
        for (int i = 0; i < 4; i++)
            for (int j = 0; j < 4; j++)
                acc[i][j] = MFMA(af[i], bf[j], acc[i][j], 0, 0, 0);
        __syncthreads();
    }
    for (int j = 0; j < 4; j++) {
        int col = n0 + wn + j * 16 + lr;
        float bv = f32 ? ((const float*)bias)[col] : b2f(((const ushort_t*)bias)[col]);
        for (int i = 0; i < 4; i++) {
            int rowb = m0 + wm + i * 16 + quad * 4;
            for (int r = 0; r < 4; r++)
                C[(size_t)(rowb + r) * NC + col] = f2b(acc[i][j][r] + bv);
        }
    }
}

// ---------------- init: kvT = 0 except row64 = ratio*eps*L; ----------------
__global__ void k_init(float* __restrict__ kvT, unsigned* __restrict__ mxk) {
    int bid = blockIdx.x, t = threadIdx.x;
    if (bid == 5120) { if (t < 64) mxk[t] = 0u; return; }
    int idx = bid * 256 + t;                    // 64*80*256 total
    int row = (idx >> 8) % 80;
    kvT[idx] = (row == 64) ? 2.56e-4f : 0.0f;   // 0.0625 * 1e-6 * 4096
}

// ---------------- k max pre-pass: max over l,m of dd_k per bh ----------------
__global__ __launch_bounds__(256) void k_kmax(const ushort_t* __restrict__ kproj,
                                              const ushort_t* __restrict__ projS,
                                              unsigned* __restrict__ mxk) {
    __shared__ ushort_t sB[64][72];
    __shared__ float wm4[4];
    int t = threadIdx.x, l0 = blockIdx.x * 64, bh = blockIdx.y;
    int b = bh >> 4, h = bh & 15;
    int w = t >> 6, lane = t & 63, lr = lane & 15, ko = (lane >> 4) * 8;
    short8 af[4][2];
    for (int i = 0; i < 4; i++)
        for (int ks = 0; ks < 2; ks++)
            af[i][ks] = *(const short8*)(projS + (size_t)(w * 64 + i * 16 + lr) * 64 + ks * 32 + ko);
    {
        int r = t >> 2, c = (t & 3) * 16;
        const short8* p = (const short8*)(kproj + (size_t)(b * 4096 + l0 + r) * 1024 + h * 64 + c);
        *(short8*)&sB[r][c] = p[0];
        *(short8*)&sB[r][c + 8] = p[1];
    }
    __syncthreads();
    f32x4 acc[4][4] = {};
    for (int j = 0; j < 4; j++)
        for (int ks = 0; ks < 2; ks++) {
            short8 bf = *(const short8*)&sB[j * 16 + lr][ks * 32 + ko];
            for (int i = 0; i < 4; i++)
                acc[i][j] = MFMA(af[i][ks], bf, acc[i][j], 0, 0, 0);
        }
    float vmax = -1e30f;
    for (int i = 0; i < 4; i++)
        for (int j = 0; j < 4; j++)
            for (int r = 0; r < 4; r++) vmax = fmaxf(vmax, acc[i][j][r]);
    for (int off = 32; off; off >>= 1) vmax = fmaxf(vmax, __shfl_xor(vmax, off, 64));
    if (lane == 0) wm4[w] = vmax;
    __syncthreads();
    if (t == 0) {
        float m = fmaxf(fmaxf(wm4[0], wm4[1]), fmaxf(wm4[2], wm4[3]));
        atomicMax(mxk + bh, encf(m));
    }
}

// ---------------- fused kv: dd=projS@k^T -> exp -> kv += vT'@expdd^T ----------
// MFMA1 operands swapped vs original: dd computed as D[l-rows][m-cols] so each
// thread's 4 reg values are 4 consecutive l for one m -> sE written as packed b64
// (8 stores/tile vs 32 scalar). sE layout + MFMA2 consumer unchanged.
__global__ __launch_bounds__(256) void k_kv(const ushort_t* __restrict__ kproj,
                                            const ushort_t* __restrict__ vproj,
                                            const ushort_t* __restrict__ projS,
                                            const unsigned* __restrict__ mxk,
                                            float* __restrict__ kvT) {
    __shared__ ushort_t sVT[80][40];
    __shared__ float    sdk[32];
    __shared__ ushort_t sK[32][72];
    __shared__ ushort_t sV[32][72];
    __shared__ ushort_t sE[256][40];
    int t = threadIdx.x, kz = blockIdx.x, bh = blockIdx.y;
    int b = bh >> 4, h = bh & 15;
    int w = t >> 6, lane = t & 63, lr = lane & 15, quad = lane >> 4, ko = quad * 8;
    float mx = decf(mxk[bh]);
    short8 af1[4][2];
    for (int i = 0; i < 4; i++)
        for (int ks = 0; ks < 2; ks++)
            af1[i][ks] = *(const short8*)(projS + (size_t)(w * 64 + i * 16 + lr) * 64 + ks * 32 + ko);
    // constant sVT rows 64..79 (row 64 = ones for normalizer) -- written once
    if (t < 128) {
        int rr = 64 + (t >> 3), cc = (t & 7) * 4;
        ushort_t val = (rr == 64) ? (ushort_t)0x3F80 : (ushort_t)0;
        for (int u = 0; u < 4; u++) sVT[rr][cc + u] = val;
    }
    f32x4 acc[5][4] = {};
    for (int lc = kz * 512; lc < kz * 512 + 512; lc += 32) {
        __syncthreads();
        {
            int r = t >> 3, c = (t & 7) * 8;
            *(short8*)&sK[r][c] = *(const short8*)(kproj + (size_t)(b * 4096 + lc + r) * 1024 + h * 64 + c);
            *(short8*)&sV[r][c] = *(const short8*)(vproj + (size_t)(b * 4096 + lc + r) * 1024 + h * 64 + c);
        }
        __syncthreads();
        if (t < 32) {   // serial per-row sum-of-squares: hidden under other waves' MFMA1
            float s = 0.f;
            for (int d2 = 0; d2 < 64; d2++) { float f = b2f(sK[t][d2]); s += f * f; }
            sdk[t] = 0.0625f * s;
        }
        short8 bf1[2][2];
        for (int j = 0; j < 2; j++)
            for (int ks = 0; ks < 2; ks++)
                bf1[j][ks] = *(const short8*)&sK[j * 16 + lr][ks * 32 + ko];
        f32x4 acc1[2][4] = {};   // swapped: D[l-rows (j,quad,r)][m-cols (i,lr)]
        for (int j = 0; j < 2; j++)
            for (int ks = 0; ks < 2; ks++)
                for (int i = 0; i < 4; i++)
                    acc1[j][i] = MFMA(bf1[j][ks], af1[i][ks], acc1[j][i], 0, 0, 0);
        {
            int d2 = t >> 2, ls = (t & 3) * 8;
            short8 pk;
            for (int u = 0; u < 8; u++) ((ushort_t*)&pk)[u] = sV[ls + u][d2];
            *(short8*)&sVT[d2][ls] = pk;
        }
        __syncthreads();
        // packed sE writes: m = w*64+i*16+lr, l = j*16+quad*4+r
        for (int i = 0; i < 4; i++) {
            int m = w * 64 + i * 16 + lr;
            for (int j = 0; j < 2; j++) {
                int lb = j * 16 + quad * 4;
                short4v pk;
                for (int r = 0; r < 4; r++)
                    ((ushort_t*)&pk)[r] = f2b(0.0625f * __expf(acc1[j][i][r] - sdk[lb + r] - mx));
                *(short4v*)&sE[m][lb] = pk;
            }
        }
        __syncthreads();
        short8 af2[5], bf2[4];
        for (int i = 0; i < 5; i++) af2[i] = *(const short8*)&sVT[i * 16 + lr][ko];
        for (int j = 0; j < 4; j++) bf2[j] = *(const short8*)&sE[w * 64 + j * 16 + lr][ko];
        for (int i = 0; i < 5; i++)
            for (int j = 0; j < 4; j++)
                acc[i][j] = MFMA(af2[i], bf2[j], acc[i][j], 0, 0, 0);
    }
    float* out = kvT + (size_t)bh * 80 * 256;
    for (int i = 0; i < 5; i++)
        for (int j = 0; j < 4; j++)
            for (int r = 0; r < 4; r++)
                atomicAdd(out + (size_t)(i * 16 + quad * 4 + r) * 256 + (w * 64 + j * 16 + lr),
                          acc[i][j][r]);
}

// ---------------- kvT finite scan + f32->bf16 convert -> fl[1] bit0 ----------------
__global__ void k_scan(const float* __restrict__ kvT, ushort_t* __restrict__ kvbf,
                       unsigned* __restrict__ fl) {
    int i4 = (blockIdx.x * 256 + threadIdx.x) * 4;   // grid 1280 * 256 * 4 = 64*80*256
    f32x4 v = *(const f32x4*)(kvT + i4);
    unsigned bad = 0;
    short4v o;
    for (int u = 0; u < 4; u++) {
        bad |= finitef(v[u]) ? 0u : 1u;
        ((ushort_t*)&o)[u] = f2b(v[u]);
    }
    if (bad) atomicOr(fl + 1, 1u);
    *(short4v*)(kvbf + i4) = o;
}

// ---------------- fused ddq + row-softmax-kernel + av + normalize ----------------
// kv panel (80x256 bf16 = 40 KB) staged once per block into LDS (aliased over dead sQ
// region); loads issued before QK MFMAs so HBM/L2 latency hides under compute (T14).
__global__ __launch_bounds__(256) void k_qav(const ushort_t* __restrict__ qproj,
                                             const ushort_t* __restrict__ projS,
                                             const ushort_t* __restrict__ kvbf,
                                             unsigned* __restrict__ fl,
                                             ushort_t* __restrict__ attn) {
    union KvQ { ushort_t kv[80][264]; ushort_t q[64][72]; };
    __shared__ KvQ sA;                 // 42240 B; q[64][72] (9216 B) aliases the front
    __shared__ ushort_t sQP[64][264];  // 33792 B
    __shared__ float    sdq[64];
    int t = threadIdx.x, l0 = blockIdx.x * 64, bh = blockIdx.y;
    int b = bh >> 4, h = bh & 15;
    int w = t >> 6, lane = t & 63, lr = lane & 15, quad = lane >> 4, ko = quad * 8;
    // stage Q tile
    {
        int r = t >> 2, c = (t & 3) * 16;
        const short8* p = (const short8*)(qproj + (size_t)(b * 4096 + l0 + r) * 1024 + h * 64 + c);
        *(short8*)&sA.q[r][c] = p[0];
        *(short8*)&sA.q[r][c + 8] = p[1];
    }
    // issue kv loads now; they complete under the QK MFMA phase
    short8 kvreg[10];
    const ushort_t* kvsrc = kvbf + (size_t)bh * 80 * 256;
    #pragma unroll
    for (int i = 0; i < 10; i++)
        kvreg[i] = *(const short8*)(kvsrc + (size_t)(i * 256 + t) * 8);
    __syncthreads();
    // A fragments + parallel row sum-of-squares (all 256 threads)
    short8 af[2];
    for (int ks = 0; ks < 2; ks++) af[ks] = *(const short8*)&sA.q[w * 16 + lr][ks * 32 + ko];
    {
        int row = t >> 2, seg = t & 3;
        short8 x0 = *(const short8*)&sA.q[row][seg * 16];
        short8 x1 = *(const short8*)&sA.q[row][seg * 16 + 8];
        float s = 0.f;
        for (int u = 0; u < 8; u++) {
            float a = b2f(((ushort_t*)&x0)[u]), c2 = b2f(((ushort_t*)&x1)[u]);
            s += a * a + c2 * c2;
        }
        s += __shfl_xor(s, 1, 64);
        s += __shfl_xor(s, 2, 64);
        if ((t & 3) == 0) sdq[row] = 0.0625f * s;
    }
    __syncthreads();   // all waves done reading sA.q; sdq visible
    // QK feature MFMAs (no LDS use -> kv loads in flight underneath)
    f32x4 acc[16] = {};
    for (int j = 0; j < 16; j++)
        for (int ks = 0; ks < 2; ks++) {
            short8 bf = *(const short8*)(projS + (size_t)(j * 16 + lr) * 64 + ks * 32 + ko);
            acc[j] = MFMA(af[ks], bf, acc[j], 0, 0, 0);
        }
    // write kv panel into LDS (overwrites dead q region)
    #pragma unroll
    for (int i = 0; i < 10; i++) {
        int c = i * 256 + t;
        *(short8*)&sA.kv[c >> 5][(c & 31) * 8] = kvreg[i];
    }
    // row max + exp features
    int rows0 = w * 16 + quad * 4;
    float rm[4], dq[4];
    for (int r = 0; r < 4; r++) {
        float m = -1e30f;
        for (int j = 0; j < 16; j++) m = fmaxf(m, acc[j][r]);
        for (int off = 1; off < 16; off <<= 1) m = fmaxf(m, __shfl_xor(m, off, 64));
        rm[r] = m;
        dq[r] = sdq[rows0 + r];
    }
    for (int j = 0; j < 16; j++)
        for (int r = 0; r < 4; r++)
            sQP[rows0 + r][j * 16 + lr] = f2b(0.0625f * (__expf(acc[j][r] - dq[r] - rm[r]) + 1e-6f));
    __syncthreads();   // kv + sQP visible
    // PV: pure LDS-fed MFMA
    f32x4 acc2[5] = {};
    for (int kt = 0; kt < 8; kt++) {
        short8 af2 = *(const short8*)&sQP[w * 16 + lr][kt * 32 + ko];
        #pragma unroll
        for (int j = 0; j < 5; j++) {
            short8 bf2 = *(const short8*)&sA.kv[j * 16 + lr][kt * 32 + ko];
            acc2[j] = MFMA(af2, bf2, acc2[j], 0, 0, 0);
        }
    }
    for (int r = 0; r < 4; r++) {
        float nv = __shfl(acc2[4][r], lane & 48, 64);  // kv row 64 = normalizer
        bool badn = !(nv > 0.0f && nv < 1e30f);
        if (badn) atomicOr(fl + 1, 2u);
        float inv = badn ? 0.0f : 1.0f / nv;
        int row = l0 + rows0 + r;
        for (int j = 0; j < 4; j++) {
            float outv = acc2[j][r] * inv;
            if (!finitef(outv)) { outv = 0.0f; atomicOr(fl + 1, 4u); }
            attn[(size_t)(b * 4096 + row) * 1024 + h * 64 + j * 16 + lr] = f2b(outv);
        }
    }
}

extern "C" void kernel_launch(void* const* d_in, const int* in_sizes, int n_in,
                              void* d_out, int out_size, void* d_ws, size_t ws_size,
                              hipStream_t stream) {
    const void* q  = d_in[0];
    const void* k  = d_in[1];
    const void* v  = d_in[2];
    const void* Wq = d_in[3];
    const void* bq = d_in[4];
    const void* Wk = d_in[5];
    const void* bk = d_in[6];
    const void* Wv = d_in[7];
    const void* bv = d_in[8];
    const void* Wo = d_in[9];
    const void* bo = d_in[10];
    const void* rf = d_in[11];

    char* wsp = (char*)d_ws;
    size_t o = 0;
    auto alloc = [&](size_t bytes) { void* p = wsp + o; o += (bytes + 255) & ~(size_t)255; return p; };
    unsigned* fl    = (unsigned*)alloc(256);                      // [0]=dtype, [1]=stage flags
    ushort_t* WT    = (ushort_t*)alloc(3ull * 1024 * 1024 * 2);   // 6.3 MB  Wq/Wk/Wv transposed
    ushort_t* WTo   = (ushort_t*)alloc(1024ull * 1024 * 2);       // 2.1 MB
    ushort_t* projS = (ushort_t*)alloc(256 * 64 * 2);
    ushort_t* kproj = (ushort_t*)alloc(16384ull * 1024 * 2);      // 32 MB (reused as attn)
    ushort_t* vproj = (ushort_t*)alloc(16384ull * 1024 * 2);      // 32 MB
    unsigned* mxk   = (unsigned*)alloc(64 * 4);
    float*    kvT   = (float*)alloc(64ull * 80 * 256 * 4);        // 5.2 MB
    ushort_t* kvbf  = (ushort_t*)alloc(64ull * 80 * 256 * 2);     // 2.6 MB bf16 kv panel
    // d_out lower 32 MB (valid for either output dtype): v/k cvt staging, then qproj.
    ushort_t* stg   = (ushort_t*)d_out;
    ushort_t* qproj = (ushort_t*)d_out;
    ushort_t* attn  = kproj;             // kproj dead after k_kv; k_qav never reads kproj

    if (ws_size < o) {  // workspace too small -> report budget in MB as sentinel
        k_fill<<<dim3((out_size + 255) / 256), 256, 0, stream>>>((ushort_t*)d_out, out_size,
                                                                 (float)(ws_size >> 20));
        return;
    }

    k_dtype<<<dim3(1), 256, 0, stream>>>((const ushort_t*)q, fl);
    k_prep<<<dim3(1025), 256, 0, stream>>>(Wq, Wk, Wv, Wo, rf, fl, WT, WTo, projS);

    // v, k: cvt into stg (lower 32MB; no-op if bf16), gload GEMM.
    k_cvt<<<dim3(8192), 256, 0, stream>>>(v, stg, fl);
    k_gemm_g<<<dim3(128, 8), 256, 0, stream>>>(stg, (const ushort_t*)v,
                                               WT + 2ull * 1048576, bv, vproj, fl, 0);
    k_cvt<<<dim3(8192), 256, 0, stream>>>(k, stg, fl);
    k_gemm_g<<<dim3(128, 8), 256, 0, stream>>>(stg, (const ushort_t*)k,
                                               WT + 1ull * 1048576, bk, kproj, fl, 0);
    // q: output occupies the staging region -> dual-dtype reg-staged A (B still gload).
    k_gemm_r<<<dim3(128, 8), 256, 0, stream>>>(q, WT + 0ull * 1048576, bq, qproj, fl);

    k_init<<<dim3(5121), 256, 0, stream>>>(kvT, mxk);
    k_kmax<<<dim3(64, 64), 256, 0, stream>>>(kproj, projS, mxk);
    k_kv<<<dim3(8, 64), 256, 0, stream>>>(kproj, vproj, projS, mxk, kvT);
    k_scan<<<dim3(1280), 256, 0, stream>>>(kvT, kvbf, fl);
    k_qav<<<dim3(64, 64), 256, 0, stream>>>(qproj, projS, kvbf, fl, attn);
    k_gemm_g<<<dim3(128, 8), 256, 0, stream>>>(attn, attn, WTo, bo, d_out, fl, 1);
}